// Round 1
// baseline (127.770 us; speedup 1.0000x reference)
//
#include <hip/hip_runtime.h>

// RgbNet split: K1 hash-grid encode (latency-bound scattered gathers, max occupancy)
//            -> feat[N][30] float4 in workspace ->
//              K2 MLP 120->64->64->64->3 (VALU/LDS-bound, unchanged structure).
// Fallback: original fused kernel if workspace is too small.

#define NSAMP 300
#define HSIZE (1u << 19)

// ---------------- K1: encode ----------------
// grid = N/8 blocks x 256 threads; __launch_bounds__(256,8) -> 8 blocks/CU = 32 waves/CU.
// Lane packing: rsub = lane>>5 (2 rays/wave), p = lane&31 (p = d*6 + l, p<30).
// The 5 samples of one (ray,level) sit in lanes p = l, l+6, ..., l+24 of the same
// half-wave, so corner-c gathers of overlapping trilinear cells coalesce to the
// same cache lines within a single instruction (HW same-line merge).
__global__ __launch_bounds__(256, 8) void rgbnet_encode(
    const float4* __restrict__ x,       // [N] rows: sx,sy,ex,ey
    const int*    __restrict__ idxf,    // [N]
    const float4* __restrict__ emb,     // [6 * 2^19] float4 entries
    float4*       __restrict__ featG,   // [N*30] float4 (ray-major)
    int N)
{
    const int tid  = threadIdx.x;
    const int lane = tid & 63;
    const int wv   = tid >> 6;                 // wave 0..3
    const int rsub = lane >> 5;                // ray sub-slot 0..1
    const int p    = lane & 31;                // pair id 0..29 (30,31 idle)
    const int ray  = blockIdx.x * 8 + wv * 2 + rsub;
    if (p >= 30 || ray >= N) return;

    const float4 xr = x[ray];
    const int d = p / 6;                       // gather offset index 0..4 (d-2 in ref)
    const int l = p - d * 6;                   // level 0..5
    int s = idxf[ray] + d - 2;
    s = max(0, min(s, NSAMP - 1));
    const float t   = (float)s * (1.0f / 299.0f);
    const float omt = 1.0f - t;
    const int   R   = 4 << l;
    const float fR  = (float)R;
    const float px = (xr.x * omt + xr.z * t) * fR;
    const float py = (xr.y * omt + xr.w * t) * fR;
    const float pz = t * fR;
    const float fx0 = floorf(px), fy0 = floorf(py), fz0 = floorf(pz);
    const float wx = px - fx0, wy = py - fy0, wz = pz - fz0;
    const int ix = (int)fx0, iy = (int)fy0, iz = (int)fz0;
    const int Rp1 = R + 1;
    const float4* __restrict__ ebase = emb + (size_t)l * HSIZE;

    float ax = 0.f, ay = 0.f, az = 0.f, aw = 0.f;
    #pragma unroll
    for (int c = 0; c < 8; ++c) {
        const int ox = (c >> 2) & 1, oy = (c >> 1) & 1, oz = c & 1;
        int cx = min(ix + ox, R); cx = max(cx, 0);
        int cy = min(iy + oy, R); cy = max(cy, 0);
        int cz = min(iz + oz, R); cz = max(cz, 0);
        unsigned idx;
        if (l < 5) {
            idx = (unsigned)(cx + cy * Rp1 + cz * Rp1 * Rp1);       // dense level
        } else {
            idx = ((unsigned)cx * 1u
                 ^ (unsigned)cy * 2654435761u
                 ^ (unsigned)cz * 805459861u) & (HSIZE - 1u);       // hashed level
        }
        const float4 e = ebase[idx];
        const float cw = (ox ? wx : 1.f - wx)
                       * (oy ? wy : 1.f - wy)
                       * (oz ? wz : 1.f - wz);
        ax = fmaf(cw, e.x, ax);
        ay = fmaf(cw, e.y, ay);
        az = fmaf(cw, e.z, az);
        aw = fmaf(cw, e.w, aw);
    }
    // ray-major: lanes p=0..29 write contiguous 480B per ray -> coalesced.
    featG[(size_t)ray * 30 + p] = make_float4(ax, ay, az, aw);
}

// ---------------- K2: MLP ----------------
// Same proven structure as the fused kernel's phases 1-4; phase 0 replaced by a
// coalesced global->LDS stage of feat (L2-resident, 30KB/block).
__global__ __launch_bounds__(1024, 1) void rgbnet_mlp(
    const float4* __restrict__ featG,
    const float* __restrict__ W1, const float* __restrict__ b1,
    const float* __restrict__ W2, const float* __restrict__ b2,
    const float* __restrict__ W3, const float* __restrict__ b3,
    const float* __restrict__ W4, const float* __restrict__ b4,
    float* __restrict__ out, int N)
{
    __shared__ float sFeat[120 * 64];   // 30720 B
    __shared__ float sHa[64 * 64];      // 16384 B
    __shared__ float sHb[64 * 64];      // 16384 B

    const int tid  = threadIdx.x;
    const int r    = tid & 63;
    const int wsub = tid >> 6;
    const int ray0 = blockIdx.x * 64;
    const int ray  = ray0 + r;

    // stage feat: 64 rays x 30 float4, transpose to [k][ray]
    for (int j = tid; j < 64 * 30; j += 1024) {
        const int rr = j / 30;
        const int k4 = j - rr * 30;
        const float4 f = featG[(size_t)(ray0 + rr) * 30 + k4];
        const int k0 = k4 * 4;
        sFeat[(k0 + 0) * 64 + rr] = f.x;
        sFeat[(k0 + 1) * 64 + rr] = f.y;
        sFeat[(k0 + 2) * 64 + rr] = f.z;
        sFeat[(k0 + 3) * 64 + rr] = f.w;
    }
    __syncthreads();

    const int wu = __builtin_amdgcn_readfirstlane(wsub);
    const int j0 = wu * 4;

    float hh[4];

    // Layer 1: 120 -> 64
    #pragma unroll
    for (int jj = 0; jj < 4; ++jj) hh[jj] = b1[j0 + jj];
    #pragma unroll 8
    for (int k = 0; k < 120; ++k) {
        const float f = sFeat[k * 64 + r];
        #pragma unroll
        for (int jj = 0; jj < 4; ++jj)
            hh[jj] = fmaf(f, W1[(j0 + jj) * 120 + k], hh[jj]);
    }
    #pragma unroll
    for (int jj = 0; jj < 4; ++jj)
        sHa[(j0 + jj) * 64 + r] = fmaxf(hh[jj], 0.f);
    __syncthreads();

    // Layer 2: 64 -> 64
    #pragma unroll
    for (int jj = 0; jj < 4; ++jj) hh[jj] = b2[j0 + jj];
    #pragma unroll 8
    for (int k = 0; k < 64; ++k) {
        const float f = sHa[k * 64 + r];
        #pragma unroll
        for (int jj = 0; jj < 4; ++jj)
            hh[jj] = fmaf(f, W2[(j0 + jj) * 64 + k], hh[jj]);
    }
    #pragma unroll
    for (int jj = 0; jj < 4; ++jj)
        sHb[(j0 + jj) * 64 + r] = fmaxf(hh[jj], 0.f);
    __syncthreads();

    // Layer 3: 64 -> 64
    #pragma unroll
    for (int jj = 0; jj < 4; ++jj) hh[jj] = b3[j0 + jj];
    #pragma unroll 8
    for (int k = 0; k < 64; ++k) {
        const float f = sHb[k * 64 + r];
        #pragma unroll
        for (int jj = 0; jj < 4; ++jj)
            hh[jj] = fmaf(f, W3[(j0 + jj) * 64 + k], hh[jj]);
    }
    #pragma unroll
    for (int jj = 0; jj < 4; ++jj)
        sHa[(j0 + jj) * 64 + r] = fmaxf(hh[jj], 0.f);
    __syncthreads();

    // Output: 64 -> 3
    if (wu < 3) {
        float acc = b4[wu];
        #pragma unroll 8
        for (int k = 0; k < 64; ++k)
            acc = fmaf(sHa[k * 64 + r], W4[wu * 64 + k], acc);
        out[(size_t)ray * 3 + wu] = acc;
    }
}

// ---------------- Fallback: original fused kernel ----------------
__global__ __launch_bounds__(1024, 1) void rgbnet_fused(
    const float4* __restrict__ x,
    const int*    __restrict__ idxf,
    const float4* __restrict__ emb,
    const float* __restrict__ W1, const float* __restrict__ b1,
    const float* __restrict__ W2, const float* __restrict__ b2,
    const float* __restrict__ W3, const float* __restrict__ b3,
    const float* __restrict__ W4, const float* __restrict__ b4,
    float* __restrict__ out, int N)
{
    __shared__ float sFeat[120 * 64];
    __shared__ float sHa[64 * 64];
    __shared__ float sHb[64 * 64];

    const int tid  = threadIdx.x;
    const int r    = tid & 63;
    const int wsub = tid >> 6;
    const int ray  = blockIdx.x * 64 + r;

    {
        const float4 xr = x[ray];
        const int    i0 = idxf[ray];
        const float sx = xr.x, sy = xr.y, ex = xr.z, ey = xr.w;

        for (int p = wsub; p < 30; p += 16) {
            const int d = p / 6;
            const int l = p - d * 6;
            int s = i0 + d - 2;
            s = max(0, min(s, NSAMP - 1));
            const float t   = (float)s * (1.0f / 299.0f);
            const float omt = 1.0f - t;
            const int   R   = 4 << l;
            const float fR  = (float)R;
            const float px = (sx * omt + ex * t) * fR;
            const float py = (sy * omt + ey * t) * fR;
            const float pz = t * fR;
            const float fx0 = floorf(px), fy0 = floorf(py), fz0 = floorf(pz);
            const float wx = px - fx0, wy = py - fy0, wz = pz - fz0;
            const int ix = (int)fx0, iy = (int)fy0, iz = (int)fz0;
            const int Rp1 = R + 1;
            const float4* __restrict__ ebase = emb + (size_t)l * HSIZE;

            float ax = 0.f, ay = 0.f, az = 0.f, aw = 0.f;
            #pragma unroll
            for (int c = 0; c < 8; ++c) {
                const int ox = (c >> 2) & 1, oy = (c >> 1) & 1, oz = c & 1;
                int cx = min(ix + ox, R); cx = max(cx, 0);
                int cy = min(iy + oy, R); cy = max(cy, 0);
                int cz = min(iz + oz, R); cz = max(cz, 0);
                unsigned idx;
                if (l < 5) {
                    idx = (unsigned)(cx + cy * Rp1 + cz * Rp1 * Rp1);
                } else {
                    idx = ((unsigned)cx * 1u
                         ^ (unsigned)cy * 2654435761u
                         ^ (unsigned)cz * 805459861u) & (HSIZE - 1u);
                }
                const float4 e = ebase[idx];
                const float cw = (ox ? wx : 1.f - wx)
                               * (oy ? wy : 1.f - wy)
                               * (oz ? wz : 1.f - wz);
                ax = fmaf(cw, e.x, ax);
                ay = fmaf(cw, e.y, ay);
                az = fmaf(cw, e.z, az);
                aw = fmaf(cw, e.w, aw);
            }
            const int k0 = p * 4;
            sFeat[(k0 + 0) * 64 + r] = ax;
            sFeat[(k0 + 1) * 64 + r] = ay;
            sFeat[(k0 + 2) * 64 + r] = az;
            sFeat[(k0 + 3) * 64 + r] = aw;
        }
    }
    __syncthreads();

    const int wu = __builtin_amdgcn_readfirstlane(wsub);
    const int j0 = wu * 4;

    float hh[4];

    #pragma unroll
    for (int jj = 0; jj < 4; ++jj) hh[jj] = b1[j0 + jj];
    #pragma unroll 8
    for (int k = 0; k < 120; ++k) {
        const float f = sFeat[k * 64 + r];
        #pragma unroll
        for (int jj = 0; jj < 4; ++jj)
            hh[jj] = fmaf(f, W1[(j0 + jj) * 120 + k], hh[jj]);
    }
    #pragma unroll
    for (int jj = 0; jj < 4; ++jj)
        sHa[(j0 + jj) * 64 + r] = fmaxf(hh[jj], 0.f);
    __syncthreads();

    #pragma unroll
    for (int jj = 0; jj < 4; ++jj) hh[jj] = b2[j0 + jj];
    #pragma unroll 8
    for (int k = 0; k < 64; ++k) {
        const float f = sHa[k * 64 + r];
        #pragma unroll
        for (int jj = 0; jj < 4; ++jj)
            hh[jj] = fmaf(f, W2[(j0 + jj) * 64 + k], hh[jj]);
    }
    #pragma unroll
    for (int jj = 0; jj < 4; ++jj)
        sHb[(j0 + jj) * 64 + r] = fmaxf(hh[jj], 0.f);
    __syncthreads();

    #pragma unroll
    for (int jj = 0; jj < 4; ++jj) hh[jj] = b3[j0 + jj];
    #pragma unroll 8
    for (int k = 0; k < 64; ++k) {
        const float f = sHb[k * 64 + r];
        #pragma unroll
        for (int jj = 0; jj < 4; ++jj)
            hh[jj] = fmaf(f, W3[(j0 + jj) * 64 + k], hh[jj]);
    }
    #pragma unroll
    for (int jj = 0; jj < 4; ++jj)
        sHa[(j0 + jj) * 64 + r] = fmaxf(hh[jj], 0.f);
    __syncthreads();

    if (wu < 3) {
        float acc = b4[wu];
        #pragma unroll 8
        for (int k = 0; k < 64; ++k)
            acc = fmaf(sHa[k * 64 + r], W4[wu * 64 + k], acc);
        out[(size_t)ray * 3 + wu] = acc;
    }
}

extern "C" void kernel_launch(void* const* d_in, const int* in_sizes, int n_in,
                              void* d_out, int out_size, void* d_ws, size_t ws_size,
                              hipStream_t stream) {
    const float4* x    = (const float4*)d_in[0];
    const int*    idxf = (const int*)   d_in[1];
    const float4* emb  = (const float4*)d_in[2];
    const float*  W1   = (const float*) d_in[3];
    const float*  b1   = (const float*) d_in[4];
    const float*  W2   = (const float*) d_in[5];
    const float*  b2   = (const float*) d_in[6];
    const float*  W3   = (const float*) d_in[7];
    const float*  b3   = (const float*) d_in[8];
    const float*  W4   = (const float*) d_in[9];
    const float*  b4   = (const float*) d_in[10];
    float* out = (float*)d_out;

    const int N = in_sizes[0] / 4;              // 16384 rays (x is [N,4])
    const size_t need = (size_t)N * 30 * sizeof(float4);   // feat workspace: 7.9 MB

    if (ws_size >= need) {
        float4* featG = (float4*)d_ws;
        hipLaunchKernelGGL(rgbnet_encode, dim3((N + 7) / 8), dim3(256), 0, stream,
                           x, idxf, emb, featG, N);
        hipLaunchKernelGGL(rgbnet_mlp, dim3((N + 63) / 64), dim3(1024), 0, stream,
                           featG, W1, b1, W2, b2, W3, b3, W4, b4, out, N);
    } else {
        hipLaunchKernelGGL(rgbnet_fused, dim3((N + 63) / 64), dim3(1024), 0, stream,
                           x, idxf, emb, W1, b1, W2, b2, W3, b3, W4, b4, out, N);
    }
}